// Round 5
// baseline (917.228 us; speedup 1.0000x reference)
//
#include <hip/hip_runtime.h>

#define B 4
#define N1 2048
#define N2 8192
#define C1 128
#define C2 64
#define K 15
#define F 128
#define S 16

// ---------------------------------------------------------------------------
// kNN: unchanged (R8-validated semantics, verified passing in round 0).
// ---------------------------------------------------------------------------
__global__ __launch_bounds__(512) void knn_kernel(
    const float* __restrict__ xyz1, const float* __restrict__ xyz2,
    unsigned short* __restrict__ nn_idx) {
#pragma clang fp contract(off)
  __shared__ float sx[N1], sy[N1], sz[N1];     // 24 KB
  __shared__ float s_cd[16][522];              // 33.4 KB (row 522: banks spread)
  __shared__ unsigned short s_ci[16][522];     // 16.7 KB
  const int b = blockIdx.y;
  const int q0 = blockIdx.x * 16;
  const int tid = threadIdx.x;

  const float* p1 = xyz1 + (size_t)b * N1 * 3;
  for (int i = tid; i < N1; i += 512) {
    sx[i] = p1[i * 3 + 0];
    sy[i] = p1[i * 3 + 1];
    sz[i] = p1[i * 3 + 2];
  }
  __syncthreads();

  const int wv = tid >> 6;
  const int lane = tid & 63;
  const int q = lane & 15;
  const int sub = lane >> 4;
  const float* p2 = xyz2 + ((size_t)b * N2 + q0 + q) * 3;
  const float qx = p2[0], qy = p2[1], qz = p2[2];

  float bd[S];
  int bi[S];
#pragma unroll
  for (int j = 0; j < S; ++j) { bd[j] = 3.4e38f; bi[j] = 0x7fffffff; }

  const int i0 = wv * 256 + sub;
  for (int ii = 0; ii < 64; ++ii) {
    const int i = i0 + (ii << 2);
    float dx = qx - sx[i];
    float dy = qy - sy[i];
    float dz = qz - sz[i];
    float d = dx * dx;
    d = d + dy * dy;
    d = d + dz * dz;
    if (d < bd[S - 1]) {   // ascending subset scan: strict < == lex (d, idx)
      bd[S - 1] = d;
      bi[S - 1] = i;
#pragma unroll
      for (int j = S - 1; j > 0; --j) {
        if (bd[j] < bd[j - 1]) {
          float td = bd[j]; bd[j] = bd[j - 1]; bd[j - 1] = td;
          int ti = bi[j]; bi[j] = bi[j - 1]; bi[j - 1] = ti;
        }
      }
    }
  }
  {
    const int ls = (wv * 4 + sub) * 16;
#pragma unroll
    for (int j = 0; j < S; ++j) {
      s_cd[q][ls + j] = bd[j];
      s_ci[q][ls + j] = (unsigned short)bi[j];
    }
  }
  __syncthreads();

  // Tree merge: L lists -> L/2, in-place (slot m), barrier-separated.
  for (int L = 32; L >= 4; L >>= 1) {
    const int half = L >> 1;
    const int nact = 16 * half;
    const int valid = tid < nact;
    float od[16];
    int oi[16];
    int q2 = 0, m = 0;
    if (valid) {
      q2 = tid / half;
      m = tid - q2 * half;
      int pa = (2 * m) * 16, ea = pa + 16;
      int pb = ea, eb = pb + 16;
#pragma unroll
      for (int j = 0; j < 16; ++j) {
        const int a_ok = pa < ea, b_ok = pb < eb;
        const int ra = a_ok ? pa : ea - 1;
        const int rb = b_ok ? pb : eb - 1;
        float da = s_cd[q2][ra];
        int ia = (int)s_ci[q2][ra];
        float db = s_cd[q2][rb];
        int ib = (int)s_ci[q2][rb];
        const int ta = a_ok && (!b_ok || da < db || (da == db && ia < ib));
        od[j] = ta ? da : db;
        oi[j] = ta ? ia : ib;
        pa += ta;
        pb += !ta;
      }
    }
    __syncthreads();
    if (valid) {
#pragma unroll
      for (int j = 0; j < 16; ++j) {
        s_cd[q2][m * 16 + j] = od[j];
        s_ci[q2][m * 16 + j] = (unsigned short)oi[j];
      }
    }
    __syncthreads();
  }

  // Final round: merge lists 0,1 -> global output (16 threads).
  if (tid < 16) {
    const int q2 = tid;
    int pa = 0, ea = 16, pb = 16, eb = 32;
    unsigned short* op = nn_idx + ((size_t)b * N2 + q0 + q2) * S;
#pragma unroll
    for (int j = 0; j < 16; ++j) {
      const int a_ok = pa < ea, b_ok = pb < eb;
      const int ra = a_ok ? pa : ea - 1;
      const int rb = b_ok ? pb : eb - 1;
      float da = s_cd[q2][ra];
      int ia = (int)s_ci[q2][ra];
      float db = s_cd[q2][rb];
      int ib = (int)s_ci[q2][rb];
      const int ta = a_ok && (!b_ok || da < db || (da == db && ia < ib));
      op[j] = (unsigned short)(ta ? ia : ib);
      pa += ta;
      pb += !ta;
    }
  }
}

// ---------------------------------------------------------------------------
// Conv, round 5: round-0 VALU compute (proven, absmax 0.03125), with two
// counter-driven, arithmetic-order-preserving fixes (bit-identical output):
//  1. K chunked 8+7: wfr live set 120 -> 64 floats => no scratch spill in
//     the GEMM k-loop (round 0 had 152+ live values vs 112 VGPR).
//  2. 2-pass cross-wave reduction: s_red [4][16][132] -> [2][16][132]; LDS
//     44.5 -> 31.2 KB => 4 blocks/CU (was 3), +33% waves for latency hiding.
// ---------------------------------------------------------------------------
__global__ __launch_bounds__(256) void conv_kernel(
    const float* __restrict__ xyz1, const float* __restrict__ feat1,
    const float* __restrict__ xyz2, const float* __restrict__ feat2,
    const float* __restrict__ kp, const float* __restrict__ W,
    const unsigned short* __restrict__ nn_idx, float* __restrict__ out) {
  __shared__ __align__(16) float s_buf[5184];   // 20.7 KB, aliased regions:
  int (*s_idx)[S] = (int(*)[S])(s_buf);                  // [0, 256)
  float (*s_rel)[S][3] = (float(*)[S][3])(s_buf + 256);  // [256, 1024)
  float (*s_w)[260] = (float(*)[260])(s_buf + 1024);     // [1024, 5184)
  float (*s_red)[16][132] = (float(*)[16][132])(s_buf);  // [0, 4224) alias
  __shared__ float s_wf[C1][20];               // 10 KB (live through k-loop)
  __shared__ float s_kp[K * 3];

  const int b = blockIdx.y;
  const int q0 = blockIdx.x * 16;
  const int tid = threadIdx.x;

  if (tid < K * 3) s_kp[tid] = kp[tid];
  s_idx[tid >> 4][tid & 15] = (int)nn_idx[((size_t)b * N2 + q0) * S + tid];
  __syncthreads();

  {
    int q = tid >> 4, s = tid & 15;
    int i = s_idx[q][s];
    const float* pn = xyz1 + ((size_t)b * N1 + i) * 3;
    const float* pq = xyz2 + ((size_t)b * N2 + q0 + q) * 3;
    s_rel[q][s][0] = pn[0] - pq[0];
    s_rel[q][s][1] = pn[1] - pq[1];
    s_rel[q][s][2] = pn[2] - pq[2];
  }
  __syncthreads();

  for (int t = tid; t < 16 * S * K; t += 256) {
    int q = t / (S * K);
    int r = t - q * (S * K);
    int s = r / K;
    int k = r - s * K;
    float rx = s_rel[q][s][0] - s_kp[k * 3 + 0];
    float ry = s_rel[q][s][1] - s_kp[k * 3 + 1];
    float rz = s_rel[q][s][2] - s_kp[k * 3 + 2];
    float d = sqrtf(fmaxf(rx * rx + ry * ry + rz * rz, 1e-12f));
    s_w[q][s * 16 + k] = fmaxf(0.0f, 1.0f - d / 0.2f);
  }
  __syncthreads();

  const int q = tid & 15;
  const int cg = tid >> 4;
  const int qg = tid >> 7;
  const int cs = (tid >> 5) & 3;
  const int fg = tid & 31;

  float4 acc[8];
#pragma unroll
  for (int qi = 0; qi < 8; ++qi) acc[qi] = make_float4(0.f, 0.f, 0.f, 0.f);

#pragma unroll
  for (int chunk = 0; chunk < 2; ++chunk) {
    const int kbase = chunk * 8;
    const int kn = chunk ? 7 : 8;

    float wfr[8][8];
#pragma unroll
    for (int kk = 0; kk < 8; ++kk)
#pragma unroll
      for (int j = 0; j < 8; ++j) wfr[kk][j] = 0.0f;

    // Phase B for this k-chunk (per-k fmac order identical to round 0).
    for (int s = 0; s < S; ++s) {
      int i = s_idx[q][s];
      const float4* fp =
          (const float4*)(feat1 + ((size_t)b * N1 + i) * C1) + cg * 2;
      float4 n0 = fp[0];
      float4 n1 = fp[1];
      const float4* wr = (const float4*)(&s_w[q][s * 16]);
      float4 wa = wr[chunk * 2 + 0];
      float4 wb = wr[chunk * 2 + 1];
      float wk[8] = {wa.x, wa.y, wa.z, wa.w, wb.x, wb.y, wb.z, wb.w};
#pragma unroll
      for (int kk = 0; kk < 8; ++kk) {
        if (kk < kn) {   // compile-time folded (kk, kn unroll-constants)
          float w = wk[kk];
          wfr[kk][0] += w * n0.x;
          wfr[kk][1] += w * n0.y;
          wfr[kk][2] += w * n0.z;
          wfr[kk][3] += w * n0.w;
          wfr[kk][4] += w * n1.x;
          wfr[kk][5] += w * n1.y;
          wfr[kk][6] += w * n1.z;
          wfr[kk][7] += w * n1.w;
        }
      }
    }

    // GEMM over this chunk's k values (inner loop identical to round 0).
#pragma unroll
    for (int kk = 0; kk < 8; ++kk) {
      if (kk < kn) {
        const int kg = kbase + kk;
        __syncthreads();
#pragma unroll
        for (int j = 0; j < 8; ++j) s_wf[cg * 8 + j][q] = wfr[kk][j];
        __syncthreads();

        const float4* Wk4 = (const float4*)(W + (size_t)kg * C1 * F) + fg;
#pragma unroll 4
        for (int c2 = 0; c2 < 32; ++c2) {
          int c = cs * 32 + c2;
          float4 wa = *(const float4*)(&s_wf[c][qg * 8 + 0]);
          float4 wb = *(const float4*)(&s_wf[c][qg * 8 + 4]);
          float4 w4 = Wk4[c * 32];
          acc[0].x += wa.x * w4.x; acc[0].y += wa.x * w4.y;
          acc[0].z += wa.x * w4.z; acc[0].w += wa.x * w4.w;
          acc[1].x += wa.y * w4.x; acc[1].y += wa.y * w4.y;
          acc[1].z += wa.y * w4.z; acc[1].w += wa.y * w4.w;
          acc[2].x += wa.z * w4.x; acc[2].y += wa.z * w4.y;
          acc[2].z += wa.z * w4.z; acc[2].w += wa.z * w4.w;
          acc[3].x += wa.w * w4.x; acc[3].y += wa.w * w4.y;
          acc[3].z += wa.w * w4.z; acc[3].w += wa.w * w4.w;
          acc[4].x += wb.x * w4.x; acc[4].y += wb.x * w4.y;
          acc[4].z += wb.x * w4.z; acc[4].w += wb.x * w4.w;
          acc[5].x += wb.y * w4.x; acc[5].y += wb.y * w4.y;
          acc[5].z += wb.y * w4.z; acc[5].w += wb.y * w4.w;
          acc[6].x += wb.z * w4.x; acc[6].y += wb.z * w4.y;
          acc[6].z += wb.z * w4.z; acc[6].w += wb.z * w4.w;
          acc[7].x += wb.w * w4.x; acc[7].y += wb.w * w4.y;
          acc[7].z += wb.w * w4.z; acc[7].w += wb.w * w4.w;
        }
      }
    }
  }

  // 2-pass reduction into s_red[2][16][132] (aliases s_idx/s_rel/s_w — all
  // dead since phase B chunk 1, >=14 barriers before the first write here).
  // Summation order ((a0+a1)+a2)+a3 preserved => bit-identical to round 0.
  const int qq0 = tid >> 5;        // item 0: qq 0..7
  const int qq1 = 8 + (tid >> 5);  // item 1: qq 8..15
  const int fj = tid & 31;

  if (cs < 2) {
#pragma unroll
    for (int qi = 0; qi < 8; ++qi)
      *(float4*)(&s_red[cs][qg * 8 + qi][fg * 4]) = acc[qi];
  }
  __syncthreads();

  float4 s01_0, s01_1;
  {
    float4 a0 = *(const float4*)&s_red[0][qq0][fj * 4];
    float4 a1 = *(const float4*)&s_red[1][qq0][fj * 4];
    s01_0.x = a0.x + a1.x; s01_0.y = a0.y + a1.y;
    s01_0.z = a0.z + a1.z; s01_0.w = a0.w + a1.w;
    float4 b0 = *(const float4*)&s_red[0][qq1][fj * 4];
    float4 b1 = *(const float4*)&s_red[1][qq1][fj * 4];
    s01_1.x = b0.x + b1.x; s01_1.y = b0.y + b1.y;
    s01_1.z = b0.z + b1.z; s01_1.w = b0.w + b1.w;
  }
  __syncthreads();
  if (cs >= 2) {
#pragma unroll
    for (int qi = 0; qi < 8; ++qi)
      *(float4*)(&s_red[cs - 2][qg * 8 + qi][fg * 4]) = acc[qi];
  }
  __syncthreads();
  {
    float4 a2 = *(const float4*)&s_red[0][qq0][fj * 4];
    float4 a3 = *(const float4*)&s_red[1][qq0][fj * 4];
    float4 v;
    v.x = fmaxf((s01_0.x + a2.x) + a3.x, 0.0f);
    v.y = fmaxf((s01_0.y + a2.y) + a3.y, 0.0f);
    v.z = fmaxf((s01_0.z + a2.z) + a3.z, 0.0f);
    v.w = fmaxf((s01_0.w + a2.w) + a3.w, 0.0f);
    ((float4*)(out + ((size_t)b * N2 + q0 + qq0) * (F + C2)))[fj] = v;
    float4 b2 = *(const float4*)&s_red[0][qq1][fj * 4];
    float4 b3 = *(const float4*)&s_red[1][qq1][fj * 4];
    float4 u;
    u.x = fmaxf((s01_1.x + b2.x) + b3.x, 0.0f);
    u.y = fmaxf((s01_1.y + b2.y) + b3.y, 0.0f);
    u.z = fmaxf((s01_1.z + b2.z) + b3.z, 0.0f);
    u.w = fmaxf((s01_1.w + b2.w) + b3.w, 0.0f);
    ((float4*)(out + ((size_t)b * N2 + q0 + qq1) * (F + C2)))[fj] = u;
  }

  {
    int qq = tid >> 4;
    int j = tid & 15;
    float4 v = ((const float4*)(feat2 + ((size_t)b * N2 + q0 + qq) * C2))[j];
    ((float4*)(out + ((size_t)b * N2 + q0 + qq) * (F + C2) + F))[j] = v;
  }
}

extern "C" void kernel_launch(void* const* d_in, const int* in_sizes, int n_in,
                              void* d_out, int out_size, void* d_ws, size_t ws_size,
                              hipStream_t stream) {
  const float* xyz1 = (const float*)d_in[0];
  const float* feat1 = (const float*)d_in[1];
  const float* xyz2 = (const float*)d_in[2];
  const float* feat2 = (const float*)d_in[3];
  const float* kp = (const float*)d_in[4];
  const float* Wm = (const float*)d_in[5];
  float* out = (float*)d_out;

  unsigned short* nn_idx = (unsigned short*)d_ws;   // 1 MB (known-safe)

  knn_kernel<<<dim3(N2 / 16, B), 512, 0, stream>>>(xyz1, xyz2, nn_idx);
  conv_kernel<<<dim3(N2 / 16, B), 256, 0, stream>>>(xyz1, feat1, xyz2, feat2,
                                                    kp, Wm, nn_idx, out);
}

// Round 6
// 658.973 us; speedup vs baseline: 1.3919x; 1.3919x over previous
//
#include <hip/hip_runtime.h>

#define B 4
#define N1 2048
#define N2 8192
#define C1 128
#define C2 64
#define K 15
#define F 128
#define S 16

// ---------------------------------------------------------------------------
// kNN: unchanged (R8-validated semantics, verified passing in rounds 0/5).
// ---------------------------------------------------------------------------
__global__ __launch_bounds__(512) void knn_kernel(
    const float* __restrict__ xyz1, const float* __restrict__ xyz2,
    unsigned short* __restrict__ nn_idx) {
#pragma clang fp contract(off)
  __shared__ float sx[N1], sy[N1], sz[N1];     // 24 KB
  __shared__ float s_cd[16][522];              // 33.4 KB (row 522: banks spread)
  __shared__ unsigned short s_ci[16][522];     // 16.7 KB
  const int b = blockIdx.y;
  const int q0 = blockIdx.x * 16;
  const int tid = threadIdx.x;

  const float* p1 = xyz1 + (size_t)b * N1 * 3;
  for (int i = tid; i < N1; i += 512) {
    sx[i] = p1[i * 3 + 0];
    sy[i] = p1[i * 3 + 1];
    sz[i] = p1[i * 3 + 2];
  }
  __syncthreads();

  const int wv = tid >> 6;
  const int lane = tid & 63;
  const int q = lane & 15;
  const int sub = lane >> 4;
  const float* p2 = xyz2 + ((size_t)b * N2 + q0 + q) * 3;
  const float qx = p2[0], qy = p2[1], qz = p2[2];

  float bd[S];
  int bi[S];
#pragma unroll
  for (int j = 0; j < S; ++j) { bd[j] = 3.4e38f; bi[j] = 0x7fffffff; }

  const int i0 = wv * 256 + sub;
  for (int ii = 0; ii < 64; ++ii) {
    const int i = i0 + (ii << 2);
    float dx = qx - sx[i];
    float dy = qy - sy[i];
    float dz = qz - sz[i];
    float d = dx * dx;
    d = d + dy * dy;
    d = d + dz * dz;
    if (d < bd[S - 1]) {   // ascending subset scan: strict < == lex (d, idx)
      bd[S - 1] = d;
      bi[S - 1] = i;
#pragma unroll
      for (int j = S - 1; j > 0; --j) {
        if (bd[j] < bd[j - 1]) {
          float td = bd[j]; bd[j] = bd[j - 1]; bd[j - 1] = td;
          int ti = bi[j]; bi[j] = bi[j - 1]; bi[j - 1] = ti;
        }
      }
    }
  }
  {
    const int ls = (wv * 4 + sub) * 16;
#pragma unroll
    for (int j = 0; j < S; ++j) {
      s_cd[q][ls + j] = bd[j];
      s_ci[q][ls + j] = (unsigned short)bi[j];
    }
  }
  __syncthreads();

  // Tree merge: L lists -> L/2, in-place (slot m), barrier-separated.
  for (int L = 32; L >= 4; L >>= 1) {
    const int half = L >> 1;
    const int nact = 16 * half;
    const int valid = tid < nact;
    float od[16];
    int oi[16];
    int q2 = 0, m = 0;
    if (valid) {
      q2 = tid / half;
      m = tid - q2 * half;
      int pa = (2 * m) * 16, ea = pa + 16;
      int pb = ea, eb = pb + 16;
#pragma unroll
      for (int j = 0; j < 16; ++j) {
        const int a_ok = pa < ea, b_ok = pb < eb;
        const int ra = a_ok ? pa : ea - 1;
        const int rb = b_ok ? pb : eb - 1;
        float da = s_cd[q2][ra];
        int ia = (int)s_ci[q2][ra];
        float db = s_cd[q2][rb];
        int ib = (int)s_ci[q2][rb];
        const int ta = a_ok && (!b_ok || da < db || (da == db && ia < ib));
        od[j] = ta ? da : db;
        oi[j] = ta ? ia : ib;
        pa += ta;
        pb += !ta;
      }
    }
    __syncthreads();
    if (valid) {
#pragma unroll
      for (int j = 0; j < 16; ++j) {
        s_cd[q2][m * 16 + j] = od[j];
        s_ci[q2][m * 16 + j] = (unsigned short)oi[j];
      }
    }
    __syncthreads();
  }

  // Final round: merge lists 0,1 -> global output (16 threads).
  if (tid < 16) {
    const int q2 = tid;
    int pa = 0, ea = 16, pb = 16, eb = 32;
    unsigned short* op = nn_idx + ((size_t)b * N2 + q0 + q2) * S;
#pragma unroll
    for (int j = 0; j < 16; ++j) {
      const int a_ok = pa < ea, b_ok = pb < eb;
      const int ra = a_ok ? pa : ea - 1;
      const int rb = b_ok ? pb : eb - 1;
      float da = s_cd[q2][ra];
      int ia = (int)s_ci[q2][ra];
      float db = s_cd[q2][rb];
      int ib = (int)s_ci[q2][rb];
      const int ta = a_ok && (!b_ok || da < db || (da == db && ia < ib));
      op[j] = (unsigned short)(ta ? ia : ib);
      pa += ta;
      pb += !ta;
    }
  }
}

// ---------------------------------------------------------------------------
// Conv, round 6: round-0 compute VERBATIM (single phase B, wfr[15][8],
// identical GEMM loop => bit-identical output, proven 385 us / 0.03125).
// Only changes vs round 0 (A/B-isolated round-5 "fix 2", which passed):
//  - s_red [4][16][132] -> [2][16][132] via 2-pass order-preserving
//    reduction: LDS 44.5 -> 31.2 KB (5 blocks/CU by LDS).
//  - __launch_bounds__(256,4): VGPR cap 128 (round 0 used 112) => 4
//    waves/SIMD => 4 blocks/CU resident (round 0: 3, LDS-limited).
// ---------------------------------------------------------------------------
__global__ __launch_bounds__(256, 4) void conv_kernel(
    const float* __restrict__ xyz1, const float* __restrict__ feat1,
    const float* __restrict__ xyz2, const float* __restrict__ feat2,
    const float* __restrict__ kp, const float* __restrict__ W,
    const unsigned short* __restrict__ nn_idx, float* __restrict__ out) {
  __shared__ __align__(16) float s_buf[5184];   // 20.7 KB, aliased regions:
  int (*s_idx)[S] = (int(*)[S])(s_buf);                  // [0, 256)
  float (*s_rel)[S][3] = (float(*)[S][3])(s_buf + 256);  // [256, 1024)
  float (*s_w)[260] = (float(*)[260])(s_buf + 1024);     // [1024, 5184)
  float (*s_red)[16][132] = (float(*)[16][132])(s_buf);  // [0, 4224) alias
  __shared__ float s_wf[C1][20];               // 10 KB (live through k-loop)
  __shared__ float s_kp[K * 3];

  const int b = blockIdx.y;
  const int q0 = blockIdx.x * 16;
  const int tid = threadIdx.x;

  if (tid < K * 3) s_kp[tid] = kp[tid];
  s_idx[tid >> 4][tid & 15] = (int)nn_idx[((size_t)b * N2 + q0) * S + tid];
  __syncthreads();

  {
    int q = tid >> 4, s = tid & 15;
    int i = s_idx[q][s];
    const float* pn = xyz1 + ((size_t)b * N1 + i) * 3;
    const float* pq = xyz2 + ((size_t)b * N2 + q0 + q) * 3;
    s_rel[q][s][0] = pn[0] - pq[0];
    s_rel[q][s][1] = pn[1] - pq[1];
    s_rel[q][s][2] = pn[2] - pq[2];
  }
  __syncthreads();

  for (int t = tid; t < 16 * S * K; t += 256) {
    int q = t / (S * K);
    int r = t - q * (S * K);
    int s = r / K;
    int k = r - s * K;
    float rx = s_rel[q][s][0] - s_kp[k * 3 + 0];
    float ry = s_rel[q][s][1] - s_kp[k * 3 + 1];
    float rz = s_rel[q][s][2] - s_kp[k * 3 + 2];
    float d = sqrtf(fmaxf(rx * rx + ry * ry + rz * rz, 1e-12f));
    s_w[q][s * 16 + k] = fmaxf(0.0f, 1.0f - d / 0.2f);
  }
  __syncthreads();

  const int q = tid & 15;
  const int cg = tid >> 4;

  float wfr[K][8];
#pragma unroll
  for (int k = 0; k < K; ++k)
#pragma unroll
    for (int j = 0; j < 8; ++j) wfr[k][j] = 0.0f;

  for (int s = 0; s < S; ++s) {
    int i = s_idx[q][s];
    const float4* fp = (const float4*)(feat1 + ((size_t)b * N1 + i) * C1) + cg * 2;
    float4 n0 = fp[0];
    float4 n1 = fp[1];
    const float4* wr = (const float4*)(&s_w[q][s * 16]);
    float4 w0 = wr[0], w1 = wr[1], w2 = wr[2], w3 = wr[3];
    float wk[16] = {w0.x, w0.y, w0.z, w0.w, w1.x, w1.y, w1.z, w1.w,
                    w2.x, w2.y, w2.z, w2.w, w3.x, w3.y, w3.z, w3.w};
#pragma unroll
    for (int k = 0; k < K; ++k) {
      float w = wk[k];
      wfr[k][0] += w * n0.x;
      wfr[k][1] += w * n0.y;
      wfr[k][2] += w * n0.z;
      wfr[k][3] += w * n0.w;
      wfr[k][4] += w * n1.x;
      wfr[k][5] += w * n1.y;
      wfr[k][6] += w * n1.z;
      wfr[k][7] += w * n1.w;
    }
  }

  const int qg = tid >> 7;
  const int cs = (tid >> 5) & 3;
  const int fg = tid & 31;
  float4 acc[8];
#pragma unroll
  for (int qi = 0; qi < 8; ++qi) acc[qi] = make_float4(0.f, 0.f, 0.f, 0.f);

  for (int k = 0; k < K; ++k) {
    __syncthreads();
#pragma unroll
    for (int j = 0; j < 8; ++j) s_wf[cg * 8 + j][q] = wfr[k][j];
    __syncthreads();

    const float4* Wk4 = (const float4*)(W + (size_t)k * C1 * F) + fg;
#pragma unroll 4
    for (int c2 = 0; c2 < 32; ++c2) {
      int c = cs * 32 + c2;
      float4 wa = *(const float4*)(&s_wf[c][qg * 8 + 0]);
      float4 wb = *(const float4*)(&s_wf[c][qg * 8 + 4]);
      float4 w4 = Wk4[c * 32];
      acc[0].x += wa.x * w4.x; acc[0].y += wa.x * w4.y;
      acc[0].z += wa.x * w4.z; acc[0].w += wa.x * w4.w;
      acc[1].x += wa.y * w4.x; acc[1].y += wa.y * w4.y;
      acc[1].z += wa.y * w4.z; acc[1].w += wa.y * w4.w;
      acc[2].x += wa.z * w4.x; acc[2].y += wa.z * w4.y;
      acc[2].z += wa.z * w4.z; acc[2].w += wa.z * w4.w;
      acc[3].x += wa.w * w4.x; acc[3].y += wa.w * w4.y;
      acc[3].z += wa.w * w4.z; acc[3].w += wa.w * w4.w;
      acc[4].x += wb.x * w4.x; acc[4].y += wb.x * w4.y;
      acc[4].z += wb.x * w4.z; acc[4].w += wb.x * w4.w;
      acc[5].x += wb.y * w4.x; acc[5].y += wb.y * w4.y;
      acc[5].z += wb.y * w4.z; acc[5].w += wb.y * w4.w;
      acc[6].x += wb.z * w4.x; acc[6].y += wb.z * w4.y;
      acc[6].z += wb.z * w4.z; acc[6].w += wb.z * w4.w;
      acc[7].x += wb.w * w4.x; acc[7].y += wb.w * w4.y;
      acc[7].z += wb.w * w4.z; acc[7].w += wb.w * w4.w;
    }
  }

  // 2-pass reduction into s_red[2][16][132] (aliases s_idx/s_rel/s_w — all
  // dead, >=30 barriers before the first write here). Summation order
  // ((a0+a1)+a2)+a3 preserved => bit-identical to round 0. Validated in R5.
  const int qq0 = tid >> 5;        // item 0: qq 0..7
  const int qq1 = 8 + (tid >> 5);  // item 1: qq 8..15
  const int fj = tid & 31;

  if (cs < 2) {
#pragma unroll
    for (int qi = 0; qi < 8; ++qi)
      *(float4*)(&s_red[cs][qg * 8 + qi][fg * 4]) = acc[qi];
  }
  __syncthreads();

  float4 s01_0, s01_1;
  {
    float4 a0 = *(const float4*)&s_red[0][qq0][fj * 4];
    float4 a1 = *(const float4*)&s_red[1][qq0][fj * 4];
    s01_0.x = a0.x + a1.x; s01_0.y = a0.y + a1.y;
    s01_0.z = a0.z + a1.z; s01_0.w = a0.w + a1.w;
    float4 b0 = *(const float4*)&s_red[0][qq1][fj * 4];
    float4 b1 = *(const float4*)&s_red[1][qq1][fj * 4];
    s01_1.x = b0.x + b1.x; s01_1.y = b0.y + b1.y;
    s01_1.z = b0.z + b1.z; s01_1.w = b0.w + b1.w;
  }
  __syncthreads();
  if (cs >= 2) {
#pragma unroll
    for (int qi = 0; qi < 8; ++qi)
      *(float4*)(&s_red[cs - 2][qg * 8 + qi][fg * 4]) = acc[qi];
  }
  __syncthreads();
  {
    float4 a2 = *(const float4*)&s_red[0][qq0][fj * 4];
    float4 a3 = *(const float4*)&s_red[1][qq0][fj * 4];
    float4 v;
    v.x = fmaxf((s01_0.x + a2.x) + a3.x, 0.0f);
    v.y = fmaxf((s01_0.y + a2.y) + a3.y, 0.0f);
    v.z = fmaxf((s01_0.z + a2.z) + a3.z, 0.0f);
    v.w = fmaxf((s01_0.w + a2.w) + a3.w, 0.0f);
    ((float4*)(out + ((size_t)b * N2 + q0 + qq0) * (F + C2)))[fj] = v;
    float4 b2 = *(const float4*)&s_red[0][qq1][fj * 4];
    float4 b3 = *(const float4*)&s_red[1][qq1][fj * 4];
    float4 u;
    u.x = fmaxf((s01_1.x + b2.x) + b3.x, 0.0f);
    u.y = fmaxf((s01_1.y + b2.y) + b3.y, 0.0f);
    u.z = fmaxf((s01_1.z + b2.z) + b3.z, 0.0f);
    u.w = fmaxf((s01_1.w + b2.w) + b3.w, 0.0f);
    ((float4*)(out + ((size_t)b * N2 + q0 + qq1) * (F + C2)))[fj] = u;
  }

  {
    int qq = tid >> 4;
    int j = tid & 15;
    float4 v = ((const float4*)(feat2 + ((size_t)b * N2 + q0 + qq) * C2))[j];
    ((float4*)(out + ((size_t)b * N2 + q0 + qq) * (F + C2) + F))[j] = v;
  }
}

extern "C" void kernel_launch(void* const* d_in, const int* in_sizes, int n_in,
                              void* d_out, int out_size, void* d_ws, size_t ws_size,
                              hipStream_t stream) {
  const float* xyz1 = (const float*)d_in[0];
  const float* feat1 = (const float*)d_in[1];
  const float* xyz2 = (const float*)d_in[2];
  const float* feat2 = (const float*)d_in[3];
  const float* kp = (const float*)d_in[4];
  const float* Wm = (const float*)d_in[5];
  float* out = (float*)d_out;

  unsigned short* nn_idx = (unsigned short*)d_ws;   // 1 MB (known-safe)

  knn_kernel<<<dim3(N2 / 16, B), 512, 0, stream>>>(xyz1, xyz2, nn_idx);
  conv_kernel<<<dim3(N2 / 16, B), 256, 0, stream>>>(xyz1, feat1, xyz2, feat2,
                                                    kp, Wm, nn_idx, out);
}

// Round 7
// 542.540 us; speedup vs baseline: 1.6906x; 1.2146x over previous
//
#include <hip/hip_runtime.h>

#define B 4
#define N1 2048
#define N2 8192
#define C1 128
#define C2 64
#define K 15
#define F 128
#define S 16

// ---------------------------------------------------------------------------
// kNN: unchanged (R8-validated semantics, verified passing in rounds 0/5/6).
// ---------------------------------------------------------------------------
__global__ __launch_bounds__(512) void knn_kernel(
    const float* __restrict__ xyz1, const float* __restrict__ xyz2,
    unsigned short* __restrict__ nn_idx) {
#pragma clang fp contract(off)
  __shared__ float sx[N1], sy[N1], sz[N1];     // 24 KB
  __shared__ float s_cd[16][522];              // 33.4 KB (row 522: banks spread)
  __shared__ unsigned short s_ci[16][522];     // 16.7 KB
  const int b = blockIdx.y;
  const int q0 = blockIdx.x * 16;
  const int tid = threadIdx.x;

  const float* p1 = xyz1 + (size_t)b * N1 * 3;
  for (int i = tid; i < N1; i += 512) {
    sx[i] = p1[i * 3 + 0];
    sy[i] = p1[i * 3 + 1];
    sz[i] = p1[i * 3 + 2];
  }
  __syncthreads();

  const int wv = tid >> 6;
  const int lane = tid & 63;
  const int q = lane & 15;
  const int sub = lane >> 4;
  const float* p2 = xyz2 + ((size_t)b * N2 + q0 + q) * 3;
  const float qx = p2[0], qy = p2[1], qz = p2[2];

  float bd[S];
  int bi[S];
#pragma unroll
  for (int j = 0; j < S; ++j) { bd[j] = 3.4e38f; bi[j] = 0x7fffffff; }

  const int i0 = wv * 256 + sub;
  for (int ii = 0; ii < 64; ++ii) {
    const int i = i0 + (ii << 2);
    float dx = qx - sx[i];
    float dy = qy - sy[i];
    float dz = qz - sz[i];
    float d = dx * dx;
    d = d + dy * dy;
    d = d + dz * dz;
    if (d < bd[S - 1]) {   // ascending subset scan: strict < == lex (d, idx)
      bd[S - 1] = d;
      bi[S - 1] = i;
#pragma unroll
      for (int j = S - 1; j > 0; --j) {
        if (bd[j] < bd[j - 1]) {
          float td = bd[j]; bd[j] = bd[j - 1]; bd[j - 1] = td;
          int ti = bi[j]; bi[j] = bi[j - 1]; bi[j - 1] = ti;
        }
      }
    }
  }
  {
    const int ls = (wv * 4 + sub) * 16;
#pragma unroll
    for (int j = 0; j < S; ++j) {
      s_cd[q][ls + j] = bd[j];
      s_ci[q][ls + j] = (unsigned short)bi[j];
    }
  }
  __syncthreads();

  // Tree merge: L lists -> L/2, in-place (slot m), barrier-separated.
  for (int L = 32; L >= 4; L >>= 1) {
    const int half = L >> 1;
    const int nact = 16 * half;
    const int valid = tid < nact;
    float od[16];
    int oi[16];
    int q2 = 0, m = 0;
    if (valid) {
      q2 = tid / half;
      m = tid - q2 * half;
      int pa = (2 * m) * 16, ea = pa + 16;
      int pb = ea, eb = pb + 16;
#pragma unroll
      for (int j = 0; j < 16; ++j) {
        const int a_ok = pa < ea, b_ok = pb < eb;
        const int ra = a_ok ? pa : ea - 1;
        const int rb = b_ok ? pb : eb - 1;
        float da = s_cd[q2][ra];
        int ia = (int)s_ci[q2][ra];
        float db = s_cd[q2][rb];
        int ib = (int)s_ci[q2][rb];
        const int ta = a_ok && (!b_ok || da < db || (da == db && ia < ib));
        od[j] = ta ? da : db;
        oi[j] = ta ? ia : ib;
        pa += ta;
        pb += !ta;
      }
    }
    __syncthreads();
    if (valid) {
#pragma unroll
      for (int j = 0; j < 16; ++j) {
        s_cd[q2][m * 16 + j] = od[j];
        s_ci[q2][m * 16 + j] = (unsigned short)oi[j];
      }
    }
    __syncthreads();
  }

  // Final round: merge lists 0,1 -> global output (16 threads).
  if (tid < 16) {
    const int q2 = tid;
    int pa = 0, ea = 16, pb = 16, eb = 32;
    unsigned short* op = nn_idx + ((size_t)b * N2 + q0 + q2) * S;
#pragma unroll
    for (int j = 0; j < 16; ++j) {
      const int a_ok = pa < ea, b_ok = pb < eb;
      const int ra = a_ok ? pa : ea - 1;
      const int rb = b_ok ? pb : eb - 1;
      float da = s_cd[q2][ra];
      int ia = (int)s_ci[q2][ra];
      float db = s_cd[q2][rb];
      int ib = (int)s_ci[q2][rb];
      const int ta = a_ok && (!b_ok || da < db || (da == db && ia < ib));
      op[j] = (unsigned short)(ta ? ia : ib);
      pa += ta;
      pb += !ta;
    }
  }
}

// ---------------------------------------------------------------------------
// Conv, round 7: round-6 kernel with ONE change — plain __launch_bounds__
// (256), reverting the (256,4) qualifier. R6 A/B showed (256,4) clamps the
// allocator to 64 VGPR (not the predicted 128) => wfr[15][8] spills to
// scratch: WRITE_SIZE 24.6->450 MB, conv 385->510 us. Round 0 proved this
// compute compiles to 112 VGPR with plain (256). With s_red shrunk to
// [2][16][132] (LDS 31.2 KB, validated bit-exact in R5/R6), 112 VGPR <= 128
// allows 4 waves/SIMD naturally => 4 blocks/CU (round 0: 3, LDS-limited).
// ---------------------------------------------------------------------------
__global__ __launch_bounds__(256) void conv_kernel(
    const float* __restrict__ xyz1, const float* __restrict__ feat1,
    const float* __restrict__ xyz2, const float* __restrict__ feat2,
    const float* __restrict__ kp, const float* __restrict__ W,
    const unsigned short* __restrict__ nn_idx, float* __restrict__ out) {
  __shared__ __align__(16) float s_buf[5184];   // 20.7 KB, aliased regions:
  int (*s_idx)[S] = (int(*)[S])(s_buf);                  // [0, 256)
  float (*s_rel)[S][3] = (float(*)[S][3])(s_buf + 256);  // [256, 1024)
  float (*s_w)[260] = (float(*)[260])(s_buf + 1024);     // [1024, 5184)
  float (*s_red)[16][132] = (float(*)[16][132])(s_buf);  // [0, 4224) alias
  __shared__ float s_wf[C1][20];               // 10 KB (live through k-loop)
  __shared__ float s_kp[K * 3];

  const int b = blockIdx.y;
  const int q0 = blockIdx.x * 16;
  const int tid = threadIdx.x;

  if (tid < K * 3) s_kp[tid] = kp[tid];
  s_idx[tid >> 4][tid & 15] = (int)nn_idx[((size_t)b * N2 + q0) * S + tid];
  __syncthreads();

  {
    int q = tid >> 4, s = tid & 15;
    int i = s_idx[q][s];
    const float* pn = xyz1 + ((size_t)b * N1 + i) * 3;
    const float* pq = xyz2 + ((size_t)b * N2 + q0 + q) * 3;
    s_rel[q][s][0] = pn[0] - pq[0];
    s_rel[q][s][1] = pn[1] - pq[1];
    s_rel[q][s][2] = pn[2] - pq[2];
  }
  __syncthreads();

  for (int t = tid; t < 16 * S * K; t += 256) {
    int q = t / (S * K);
    int r = t - q * (S * K);
    int s = r / K;
    int k = r - s * K;
    float rx = s_rel[q][s][0] - s_kp[k * 3 + 0];
    float ry = s_rel[q][s][1] - s_kp[k * 3 + 1];
    float rz = s_rel[q][s][2] - s_kp[k * 3 + 2];
    float d = sqrtf(fmaxf(rx * rx + ry * ry + rz * rz, 1e-12f));
    s_w[q][s * 16 + k] = fmaxf(0.0f, 1.0f - d / 0.2f);
  }
  __syncthreads();

  const int q = tid & 15;
  const int cg = tid >> 4;

  float wfr[K][8];
#pragma unroll
  for (int k = 0; k < K; ++k)
#pragma unroll
    for (int j = 0; j < 8; ++j) wfr[k][j] = 0.0f;

  for (int s = 0; s < S; ++s) {
    int i = s_idx[q][s];
    const float4* fp = (const float4*)(feat1 + ((size_t)b * N1 + i) * C1) + cg * 2;
    float4 n0 = fp[0];
    float4 n1 = fp[1];
    const float4* wr = (const float4*)(&s_w[q][s * 16]);
    float4 w0 = wr[0], w1 = wr[1], w2 = wr[2], w3 = wr[3];
    float wk[16] = {w0.x, w0.y, w0.z, w0.w, w1.x, w1.y, w1.z, w1.w,
                    w2.x, w2.y, w2.z, w2.w, w3.x, w3.y, w3.z, w3.w};
#pragma unroll
    for (int k = 0; k < K; ++k) {
      float w = wk[k];
      wfr[k][0] += w * n0.x;
      wfr[k][1] += w * n0.y;
      wfr[k][2] += w * n0.z;
      wfr[k][3] += w * n0.w;
      wfr[k][4] += w * n1.x;
      wfr[k][5] += w * n1.y;
      wfr[k][6] += w * n1.z;
      wfr[k][7] += w * n1.w;
    }
  }

  const int qg = tid >> 7;
  const int cs = (tid >> 5) & 3;
  const int fg = tid & 31;
  float4 acc[8];
#pragma unroll
  for (int qi = 0; qi < 8; ++qi) acc[qi] = make_float4(0.f, 0.f, 0.f, 0.f);

  for (int k = 0; k < K; ++k) {
    __syncthreads();
#pragma unroll
    for (int j = 0; j < 8; ++j) s_wf[cg * 8 + j][q] = wfr[k][j];
    __syncthreads();

    const float4* Wk4 = (const float4*)(W + (size_t)k * C1 * F) + fg;
#pragma unroll 4
    for (int c2 = 0; c2 < 32; ++c2) {
      int c = cs * 32 + c2;
      float4 wa = *(const float4*)(&s_wf[c][qg * 8 + 0]);
      float4 wb = *(const float4*)(&s_wf[c][qg * 8 + 4]);
      float4 w4 = Wk4[c * 32];
      acc[0].x += wa.x * w4.x; acc[0].y += wa.x * w4.y;
      acc[0].z += wa.x * w4.z; acc[0].w += wa.x * w4.w;
      acc[1].x += wa.y * w4.x; acc[1].y += wa.y * w4.y;
      acc[1].z += wa.y * w4.z; acc[1].w += wa.y * w4.w;
      acc[2].x += wa.z * w4.x; acc[2].y += wa.z * w4.y;
      acc[2].z += wa.z * w4.z; acc[2].w += wa.z * w4.w;
      acc[3].x += wa.w * w4.x; acc[3].y += wa.w * w4.y;
      acc[3].z += wa.w * w4.z; acc[3].w += wa.w * w4.w;
      acc[4].x += wb.x * w4.x; acc[4].y += wb.x * w4.y;
      acc[4].z += wb.x * w4.z; acc[4].w += wb.x * w4.w;
      acc[5].x += wb.y * w4.x; acc[5].y += wb.y * w4.y;
      acc[5].z += wb.y * w4.z; acc[5].w += wb.y * w4.w;
      acc[6].x += wb.z * w4.x; acc[6].y += wb.z * w4.y;
      acc[6].z += wb.z * w4.z; acc[6].w += wb.z * w4.w;
      acc[7].x += wb.w * w4.x; acc[7].y += wb.w * w4.y;
      acc[7].z += wb.w * w4.z; acc[7].w += wb.w * w4.w;
    }
  }

  // 2-pass reduction into s_red[2][16][132] (aliases s_idx/s_rel/s_w — all
  // dead, >=30 barriers before the first write here). Summation order
  // ((a0+a1)+a2)+a3 preserved => bit-identical to round 0. Validated R5/R6.
  const int qq0 = tid >> 5;        // item 0: qq 0..7
  const int qq1 = 8 + (tid >> 5);  // item 1: qq 8..15
  const int fj = tid & 31;

  if (cs < 2) {
#pragma unroll
    for (int qi = 0; qi < 8; ++qi)
      *(float4*)(&s_red[cs][qg * 8 + qi][fg * 4]) = acc[qi];
  }
  __syncthreads();

  float4 s01_0, s01_1;
  {
    float4 a0 = *(const float4*)&s_red[0][qq0][fj * 4];
    float4 a1 = *(const float4*)&s_red[1][qq0][fj * 4];
    s01_0.x = a0.x + a1.x; s01_0.y = a0.y + a1.y;
    s01_0.z = a0.z + a1.z; s01_0.w = a0.w + a1.w;
    float4 b0 = *(const float4*)&s_red[0][qq1][fj * 4];
    float4 b1 = *(const float4*)&s_red[1][qq1][fj * 4];
    s01_1.x = b0.x + b1.x; s01_1.y = b0.y + b1.y;
    s01_1.z = b0.z + b1.z; s01_1.w = b0.w + b1.w;
  }
  __syncthreads();
  if (cs >= 2) {
#pragma unroll
    for (int qi = 0; qi < 8; ++qi)
      *(float4*)(&s_red[cs - 2][qg * 8 + qi][fg * 4]) = acc[qi];
  }
  __syncthreads();
  {
    float4 a2 = *(const float4*)&s_red[0][qq0][fj * 4];
    float4 a3 = *(const float4*)&s_red[1][qq0][fj * 4];
    float4 v;
    v.x = fmaxf((s01_0.x + a2.x) + a3.x, 0.0f);
    v.y = fmaxf((s01_0.y + a2.y) + a3.y, 0.0f);
    v.z = fmaxf((s01_0.z + a2.z) + a3.z, 0.0f);
    v.w = fmaxf((s01_0.w + a2.w) + a3.w, 0.0f);
    ((float4*)(out + ((size_t)b * N2 + q0 + qq0) * (F + C2)))[fj] = v;
    float4 b2 = *(const float4*)&s_red[0][qq1][fj * 4];
    float4 b3 = *(const float4*)&s_red[1][qq1][fj * 4];
    float4 u;
    u.x = fmaxf((s01_1.x + b2.x) + b3.x, 0.0f);
    u.y = fmaxf((s01_1.y + b2.y) + b3.y, 0.0f);
    u.z = fmaxf((s01_1.z + b2.z) + b3.z, 0.0f);
    u.w = fmaxf((s01_1.w + b2.w) + b3.w, 0.0f);
    ((float4*)(out + ((size_t)b * N2 + q0 + qq1) * (F + C2)))[fj] = u;
  }

  {
    int qq = tid >> 4;
    int j = tid & 15;
    float4 v = ((const float4*)(feat2 + ((size_t)b * N2 + q0 + qq) * C2))[j];
    ((float4*)(out + ((size_t)b * N2 + q0 + qq) * (F + C2) + F))[j] = v;
  }
}

extern "C" void kernel_launch(void* const* d_in, const int* in_sizes, int n_in,
                              void* d_out, int out_size, void* d_ws, size_t ws_size,
                              hipStream_t stream) {
  const float* xyz1 = (const float*)d_in[0];
  const float* feat1 = (const float*)d_in[1];
  const float* xyz2 = (const float*)d_in[2];
  const float* feat2 = (const float*)d_in[3];
  const float* kp = (const float*)d_in[4];
  const float* Wm = (const float*)d_in[5];
  float* out = (float*)d_out;

  unsigned short* nn_idx = (unsigned short*)d_ws;   // 1 MB (known-safe)

  knn_kernel<<<dim3(N2 / 16, B), 512, 0, stream>>>(xyz1, xyz2, nn_idx);
  conv_kernel<<<dim3(N2 / 16, B), 256, 0, stream>>>(xyz1, feat1, xyz2, feat2,
                                                    kp, Wm, nn_idx, out);
}